// Round 12
// baseline (218.124 us; speedup 1.0000x reference)
//
#include <hip/hip_runtime.h>
#include <math.h>

// B=1, I=J=256, C=128, H=4, CH=32
#define NI 256
#define NJ 256
#define NC 128
#define NH 4
#define NCH 32
#define TOKS ((long)NI * NJ)

typedef __attribute__((ext_vector_type(8)))  __bf16        bf16x8;
typedef __attribute__((ext_vector_type(8)))  unsigned short u16x8;
typedef __attribute__((ext_vector_type(4)))  unsigned int   u32x4;
typedef __attribute__((ext_vector_type(16))) float         f32x16;

__device__ __forceinline__ unsigned short f2bf(float f) {
    unsigned u = __builtin_bit_cast(unsigned, f);
    u += 0x7fffu + ((u >> 16) & 1u);          // RNE
    return (unsigned short)(u >> 16);
}
__device__ __forceinline__ float bf2f(unsigned short s) {
    return __builtin_bit_cast(float, ((unsigned)s) << 16);
}
__device__ __forceinline__ float exp2_fast(float x) {
    float r;
    asm("v_exp_f32 %0, %1" : "=v"(r) : "v"(x));   // D = 2^S0
    return r;
}
__device__ __forceinline__ f32x16 fzero16() {
    f32x16 z;
#pragma unroll
    for (int r = 0; r < 16; ++r) z[r] = 0.f;
    return z;
}
__device__ __forceinline__ f32x16 mfma16(bf16x8 a, bf16x8 b, f32x16 c) {
    return __builtin_amdgcn_mfma_f32_32x32x16_bf16(a, b, c, 0, 0, 0);
}

#define LOG2E 1.4426950408889634f
#define QSCALE 0.25503486f   // CH^-0.5 * log2e

// ---------------------------------------------------------------------------
// Kernel 0: transpose+convert weights to bf16. w_tri pre-scaled by log2e.
// ---------------------------------------------------------------------------
__global__ __launch_bounds__(256) void convert_weights(
    const float* __restrict__ wq, const float* __restrict__ wk,
    const float* __restrict__ wv, const float* __restrict__ wg,
    const float* __restrict__ wo, const float* __restrict__ w_tri,
    unsigned short* __restrict__ Wt_all, unsigned short* __restrict__ Wto,
    unsigned short* __restrict__ Wtri_pad)
{
    int id = blockIdx.x * 256 + threadIdx.x;          // 0..86015
    if (id < 4 * 16384) {
        int m = id >> 14, r = id & 16383;
        int kk = r >> 7, c = r & 127;
        const float* W = (m == 0) ? wq : (m == 1) ? wk : (m == 2) ? wv : wg;
        Wt_all[(m * 128 + c) * 128 + kk] = f2bf(W[kk * 128 + c]);
    } else if (id < 5 * 16384) {
        int r = id - 4 * 16384;
        int kk = r >> 7, c = r & 127;
        Wto[c * 128 + kk] = f2bf(wo[kk * 128 + c]);
    } else {
        int r = id - 5 * 16384;                        // 0..4095
        int col = r >> 7, kk = r & 127;
        Wtri_pad[col * 128 + kk] = (col < NH) ? f2bf(w_tri[kk * NH + col] * LOG2E)
                                              : (unsigned short)0;
    }
}

// ---------------------------------------------------------------------------
// Kernel 1: LayerNorm + tri bias via MFMA -> tswz (pre-swizzled).
// ---------------------------------------------------------------------------
#define XNP 136
__global__ __launch_bounds__(256, 2) void ln_tri(
    const float* __restrict__ x, const float* __restrict__ ln_w, const float* __restrict__ ln_b,
    const unsigned short* __restrict__ Wtri_pad, float* __restrict__ tswz)
{
    __shared__ unsigned short xn[64 * XNP];   // ~17.4 KB
    const int tid = threadIdx.x;
    const long tok0 = (long)blockIdx.x * 64;

    const int lane8 = tid & 7;
#pragma unroll
    for (int p = 0; p < 2; ++p) {
        const int t = p * 32 + (tid >> 3);
        const float4* xrow = (const float4*)(x + (tok0 + t) * NC + lane8 * 16);
        float4 xv[4];
        float s = 0.f;
#pragma unroll
        for (int u = 0; u < 4; ++u) {
            xv[u] = xrow[u];
            s += xv[u].x + xv[u].y + xv[u].z + xv[u].w;
        }
#pragma unroll
        for (int off = 4; off; off >>= 1) s += __shfl_down(s, off, 8);
        const float mu = __shfl(s, 0, 8) * (1.f / (float)NC);
        float s2 = 0.f;
#pragma unroll
        for (int u = 0; u < 4; ++u) {
            float dx;
            dx = xv[u].x - mu; s2 += dx * dx;
            dx = xv[u].y - mu; s2 += dx * dx;
            dx = xv[u].z - mu; s2 += dx * dx;
            dx = xv[u].w - mu; s2 += dx * dx;
        }
#pragma unroll
        for (int off = 4; off; off >>= 1) s2 += __shfl_down(s2, off, 8);
        const float rstd = rsqrtf(__shfl(s2, 0, 8) * (1.f / (float)NC) + 1e-5f);
#pragma unroll
        for (int u = 0; u < 4; ++u) {
            const int c = lane8 * 16 + u * 4;
            const float4 lw = *(const float4*)(ln_w + c);
            const float4 lb = *(const float4*)(ln_b + c);
            float o0 = (xv[u].x - mu) * rstd * lw.x + lb.x;
            float o1 = (xv[u].y - mu) * rstd * lw.y + lb.y;
            float o2 = (xv[u].z - mu) * rstd * lw.z + lb.z;
            float o3 = (xv[u].w - mu) * rstd * lw.w + lb.w;
            unsigned p0 = (unsigned)f2bf(o0) | ((unsigned)f2bf(o1) << 16);
            unsigned p1 = (unsigned)f2bf(o2) | ((unsigned)f2bf(o3) << 16);
            *(unsigned*)&xn[t * XNP + c]     = p0;
            *(unsigned*)&xn[t * XNP + c + 2] = p1;
        }
    }
    __syncthreads();

    const int L = tid & 63, lh = L >> 5, lc = L & 31;
    f32x16 accT[2];
    accT[0] = fzero16();
    accT[1] = fzero16();

#pragma unroll
    for (int k0 = 0; k0 < 8; ++k0) {
        bf16x8 a0 = *(const bf16x8*)&xn[(lc)      * XNP + k0 * 16 + lh * 8];
        bf16x8 a1 = *(const bf16x8*)&xn[(32 + lc) * XNP + k0 * 16 + lh * 8];
        bf16x8 bt = *(const bf16x8*)&Wtri_pad[lc * 128 + k0 * 16 + lh * 8];
        accT[0] = mfma16(a0, bt, accT[0]);
        accT[1] = mfma16(a1, bt, accT[1]);
    }

    const int a_row = (int)(tok0 >> 8);
    const int b0    = (int)(tok0 & 255);
    if (lc < NH) {
        const int qt_i = a_row >> 5;
        const int lsw  = ((a_row & 31) + 32 * lh) * 16;
#pragma unroll
        for (int mt = 0; mt < 2; ++mt) {
            float* dst = tswz + ((long)((lc * 8 + qt_i) * 8 + (b0 >> 5) + mt)) * 1024 + lsw;
#pragma unroll
            for (int u = 0; u < 4; ++u)
                *(float4*)(dst + u * 4) = make_float4(accT[mt][4*u],   accT[mt][4*u+1],
                                                      accT[mt][4*u+2], accT[mt][4*u+3]);
        }
    }
}

// ---------------------------------------------------------------------------
// Kernel 2: FUSED LN + projections + attention + gating + out-proj.
// v4: 1024 threads = 16 waves = 2 WAVE-GROUPS of 8. Group g handles heads
// {g, g+2} with its own Ks/Vt LDS set -> per-wave serial chain halves and
// occupancy doubles (2 -> 4 waves/SIMD; the latency-bound fix).
// Epilogue sums the two groups' partial out^T. Per-wave code identical to
// R11 (VGPR 108, fits the 128 cap at 4 waves/SIMD; spill tripwire WRITE_SIZE).
// LDS: xn 69632 | Ks 2x20480 | Vt 2x16896 | maskb 1024 = 145408 B (1 blk/CU).
// ---------------------------------------------------------------------------
#define KSP 40    // Ks row stride (shorts)
#define VTP 264   // Vt row stride (shorts)
#define OSP 36    // outs row stride (floats)
__global__ __launch_bounds__(1024, 1) void attn_mega(
    const float* __restrict__ x, const float* __restrict__ ln_w, const float* __restrict__ ln_b,
    const unsigned short* __restrict__ Wt_all, const float* __restrict__ tswz,
    const float* __restrict__ mask, const unsigned short* __restrict__ Wto,
    const float* __restrict__ bg, const float* __restrict__ bo,
    float* __restrict__ out)
{
    __shared__ char smem[145408];
    unsigned short* xn = (unsigned short*)smem;              // [0, 69632)
    float*       maskb = (float*)(smem + 144384);            // 1024 B

    const int i = blockIdx.x;
    const int tid = threadIdx.x;                 // 0..1023
    const int w16 = tid >> 6;                    // wave 0..15
    const int g = w16 >> 3;                      // wave-group 0/1
    const int w = w16 & 7;                       // q-tile within group
    const int L = tid & 63, lh = L >> 5, lc = L & 31;

    unsigned short* Ks = (unsigned short*)(smem + 69632 + g * 20480);
    unsigned short* Vt = (unsigned short*)(smem + 110592 + g * 16896);
    float* outsg = (float*)(smem + g * 36864);   // epilogue region per group

    if (tid < NJ) maskb[tid] = (1.0e9f * LOG2E) * (mask[i * NJ + tid] - 1.0f);

    // ---- LayerNorm the row's 256 tokens into LDS (8 lanes per token) ----
    const int lane8 = tid & 7;
#pragma unroll
    for (int p = 0; p < 2; ++p) {
        const int t = p * 128 + (tid >> 3);
        const float4* xrow = (const float4*)(x + ((long)i * NJ + t) * NC + lane8 * 16);
        float4 xv[4];
        float s = 0.f;
#pragma unroll
        for (int u = 0; u < 4; ++u) {
            xv[u] = xrow[u];
            s += xv[u].x + xv[u].y + xv[u].z + xv[u].w;
        }
#pragma unroll
        for (int off = 4; off; off >>= 1) s += __shfl_down(s, off, 8);
        const float mu = __shfl(s, 0, 8) * (1.f / (float)NC);
        float s2 = 0.f;
#pragma unroll
        for (int u = 0; u < 4; ++u) {
            float dx;
            dx = xv[u].x - mu; s2 += dx * dx;
            dx = xv[u].y - mu; s2 += dx * dx;
            dx = xv[u].z - mu; s2 += dx * dx;
            dx = xv[u].w - mu; s2 += dx * dx;
        }
#pragma unroll
        for (int off = 4; off; off >>= 1) s2 += __shfl_down(s2, off, 8);
        const float rstd = rsqrtf(__shfl(s2, 0, 8) * (1.f / (float)NC) + 1e-5f);
#pragma unroll
        for (int u = 0; u < 4; ++u) {
            const int c = lane8 * 16 + u * 4;
            const float4 lw = *(const float4*)(ln_w + c);
            const float4 lb = *(const float4*)(ln_b + c);
            float o0 = (xv[u].x - mu) * rstd * lw.x + lb.x;
            float o1 = (xv[u].y - mu) * rstd * lw.y + lb.y;
            float o2 = (xv[u].z - mu) * rstd * lw.z + lb.z;
            float o3 = (xv[u].w - mu) * rstd * lw.w + lb.w;
            unsigned p0 = (unsigned)f2bf(o0) | ((unsigned)f2bf(o1) << 16);
            unsigned p1 = (unsigned)f2bf(o2) | ((unsigned)f2bf(o3) << 16);
            *(unsigned*)&xn[t * XNP + c]     = p0;
            *(unsigned*)&xn[t * XNP + c + 2] = p1;
        }
    }
    __syncthreads();

    int rowl[16];
#pragma unroll
    for (int r = 0; r < 16; ++r) rowl[r] = (r & 3) + 8 * (r >> 2) + 4 * lh;

    f32x16 outacc[4];
#pragma unroll
    for (int ct = 0; ct < 4; ++ct) outacc[ct] = fzero16();

#pragma unroll 1
    for (int hh = 0; hh < 2; ++hh) {
        const int h = g + 2 * hh;             // group 0: heads 0,2; group 1: 1,3
        const unsigned short* xnrow = xn + (w * 32 + lc) * XNP;

        // ---- pass 1: k + v projections (accs die at scatter) ----
        {
            f32x16 kacc = fzero16(), vacc = fzero16();
            const unsigned short* Wk = Wt_all + ((1 * 128 + h * 32 + lc) * 128);
            const unsigned short* Wv = Wt_all + ((2 * 128 + h * 32 + lc) * 128);
#pragma unroll
            for (int k0 = 0; k0 < 8; ++k0) {
                const int ko = k0 * 16 + lh * 8;
                const bf16x8 xf = *(const bf16x8*)&xnrow[ko];
                kacc = mfma16(*(const bf16x8*)&Wk[ko], xf, kacc);  // C[reg=ch][lane=token]
                vacc = mfma16(xf, *(const bf16x8*)&Wv[ko], vacc);  // C[reg=token][lane=ch]
            }
            if (hh) __syncthreads();          // prev head's Ks/Vt readers done
#pragma unroll
            for (int j = 0; j < 8; ++j) {
                const unsigned pr = (unsigned)f2bf(kacc[2*j])
                                  | ((unsigned)f2bf(kacc[2*j+1]) << 16);
                const int off = 8 * (j >> 1) + 4 * lh + 2 * (j & 1);
                *(unsigned*)&Ks[(w * 32 + lc) * KSP + off] = pr;
            }
#pragma unroll
            for (int r = 0; r < 16; ++r)
                Vt[lc * VTP + w * 32 + rowl[r]] = f2bf(vacc[r]);
        }

        // ---- pass 2: q + g projections ----
        bf16x8 a0, a1;
        unsigned gp[8];                       // gate, packed bf16 pairs
        {
            f32x16 qacc = fzero16(), gacc = fzero16();
            const unsigned short* Wq = Wt_all + ((0 * 128 + h * 32 + lc) * 128);
            const unsigned short* Wg = Wt_all + ((3 * 128 + h * 32 + lc) * 128);
#pragma unroll
            for (int k0 = 0; k0 < 8; ++k0) {
                const int ko = k0 * 16 + lh * 8;
                const bf16x8 xf = *(const bf16x8*)&xnrow[ko];
                qacc = mfma16(*(const bf16x8*)&Wq[ko], xf, qacc);  // swapped
                gacc = mfma16(*(const bf16x8*)&Wg[ko], xf, gacc);  // swapped
            }
            unsigned pkq[8];
#pragma unroll
            for (int j = 0; j < 8; ++j)
                pkq[j] = (unsigned)f2bf(qacc[2*j] * QSCALE)
                       | ((unsigned)f2bf(qacc[2*j+1] * QSCALE) << 16);
#pragma unroll
            for (int ss = 0; ss < 2; ++ss) {
                const unsigned give0 = lh ? pkq[4*ss]     : pkq[4*ss + 2];
                const unsigned give1 = lh ? pkq[4*ss + 1] : pkq[4*ss + 3];
                const unsigned t0 = __shfl_xor(give0, 32);
                const unsigned t1 = __shfl_xor(give1, 32);
                u32x4 bw;
                bw[0] = lh ? t0 : pkq[4*ss];
                bw[1] = lh ? t1 : pkq[4*ss + 1];
                bw[2] = lh ? pkq[4*ss + 2] : t0;
                bw[3] = lh ? pkq[4*ss + 3] : t1;
                if (ss == 0) a0 = __builtin_bit_cast(bf16x8, bw);
                else         a1 = __builtin_bit_cast(bf16x8, bw);
            }
#pragma unroll
            for (int gg = 0; gg < 4; ++gg) {
                const float4 b4 = *(const float4*)(bg + h * 32 + gg * 8 + 4 * lh);
                const float g0 = __builtin_amdgcn_rcpf(1.f + __expf(-(gacc[4*gg + 0] + b4.x)));
                const float g1 = __builtin_amdgcn_rcpf(1.f + __expf(-(gacc[4*gg + 1] + b4.y)));
                const float g2 = __builtin_amdgcn_rcpf(1.f + __expf(-(gacc[4*gg + 2] + b4.z)));
                const float g3 = __builtin_amdgcn_rcpf(1.f + __expf(-(gacc[4*gg + 3] + b4.w)));
                gp[2*gg]     = (unsigned)f2bf(g0) | ((unsigned)f2bf(g1) << 16);
                gp[2*gg + 1] = (unsigned)f2bf(g2) | ((unsigned)f2bf(g3) << 16);
            }
        }

        const float* tbase = tswz + ((long)(h * 8 + w) * 8) * 1024 + (long)L * 16;
        __syncthreads();                      // Ks/Vt staged (both groups)

        // ---- t-loop (proven code) ----
        float ls = 0.f;
        f32x16 O = fzero16();
#pragma unroll
        for (int t = 0; t < 8; ++t) {
            bf16x8 kb0 = *(const bf16x8*)&Ks[(t * 32 + lc) * KSP + lh * 8];
            bf16x8 kb1 = *(const bf16x8*)&Ks[(t * 32 + lc) * KSP + 16 + lh * 8];
            f32x16 s = fzero16();
            s = mfma16(kb0, a0, s);
            s = mfma16(kb1, a1, s);

            unsigned pk[8];
            const float* tv = tbase + (long)t * 1024;
#pragma unroll
            for (int gg = 0; gg < 4; ++gg) {
                const float4 tb = *(const float4*)(tv + gg * 4);
                const float4 mb = *(const float4*)&maskb[t * 32 + gg * 8 + 4 * lh];
                const float p0 = exp2_fast(fminf(s[4*gg + 0] + tb.x + mb.x, 43.4f));
                const float p1 = exp2_fast(fminf(s[4*gg + 1] + tb.y + mb.y, 43.4f));
                const float p2 = exp2_fast(fminf(s[4*gg + 2] + tb.z + mb.z, 43.4f));
                const float p3 = exp2_fast(fminf(s[4*gg + 3] + tb.w + mb.w, 43.4f));
                ls += (p0 + p1) + (p2 + p3);
                pk[2*gg]     = (unsigned)f2bf(p0) | ((unsigned)f2bf(p1) << 16);
                pk[2*gg + 1] = (unsigned)f2bf(p2) | ((unsigned)f2bf(p3) << 16);
            }

#pragma unroll
            for (int ss = 0; ss < 2; ++ss) {
                const unsigned give0 = lh ? pk[4*ss]     : pk[4*ss + 2];
                const unsigned give1 = lh ? pk[4*ss + 1] : pk[4*ss + 3];
                const unsigned t0 = __shfl_xor(give0, 32);
                const unsigned t1 = __shfl_xor(give1, 32);
                u32x4 bw;
                bw[0] = lh ? t0 : pk[4*ss];
                bw[1] = lh ? t1 : pk[4*ss + 1];
                bw[2] = lh ? pk[4*ss + 2] : t0;
                bw[3] = lh ? pk[4*ss + 3] : t1;
                const bf16x8 pb = __builtin_bit_cast(bf16x8, bw);
                const bf16x8 va = *(const bf16x8*)&Vt[lc * VTP + t * 32 + ss * 16 + lh * 8];
                O = mfma16(va, pb, O);
            }
        }

        // ---- normalize + gate (packed bf16 gate) ----
        ls += __shfl_xor(ls, 32);
        const float rl = __builtin_amdgcn_rcpf(ls);
        unsigned pk2[8];
#pragma unroll
        for (int j = 0; j < 8; ++j) {
            const float o0 = O[2*j]     * rl * bf2f((unsigned short)(gp[j] & 0xffffu));
            const float o1 = O[2*j + 1] * rl * bf2f((unsigned short)(gp[j] >> 16));
            pk2[j] = (unsigned)f2bf(o0) | ((unsigned)f2bf(o1) << 16);
        }

        // ---- out^T += Wo_h^T @ OG_h^T ----
#pragma unroll
        for (int ss = 0; ss < 2; ++ss) {
            const unsigned give0 = lh ? pk2[4*ss]     : pk2[4*ss + 2];
            const unsigned give1 = lh ? pk2[4*ss + 1] : pk2[4*ss + 3];
            const unsigned t0 = __shfl_xor(give0, 32);
            const unsigned t1 = __shfl_xor(give1, 32);
            u32x4 bw;
            bw[0] = lh ? t0 : pk2[4*ss];
            bw[1] = lh ? t1 : pk2[4*ss + 1];
            bw[2] = lh ? pk2[4*ss + 2] : t0;
            bw[3] = lh ? pk2[4*ss + 3] : t1;
            const bf16x8 ogb = __builtin_bit_cast(bf16x8, bw);
#pragma unroll
            for (int ct = 0; ct < 4; ++ct) {
                const bf16x8 wa = *(const bf16x8*)&Wto[(ct * 32 + lc) * 128 + h * 32 + ss * 16 + lh * 8];
                outacc[ct] = mfma16(wa, ogb, outacc[ct]);
            }
        }
    }

    // ---- epilogue: per cout-tile, stage both groups' partials, sum, store ----
#pragma unroll
    for (int ct = 0; ct < 4; ++ct) {
        __syncthreads();                      // all t-loop/LDS readers done
#pragma unroll
        for (int r = 0; r < 16; ++r)
            outsg[(w * 32 + lc) * OSP + rowl[r]] = outacc[ct][r];
        __syncthreads();
        const float* outs0 = (const float*)smem;
        const float* outs1 = (const float*)(smem + 36864);
#pragma unroll
        for (int it = 0; it < 2; ++it) {
            const int fi = it * 1024 + tid;   // 0..2047 float4s
            const int row = fi >> 3, c4 = fi & 7;
            const float4 v0 = *(const float4*)&outs0[row * OSP + c4 * 4];
            const float4 v1 = *(const float4*)&outs1[row * OSP + c4 * 4];
            const float4 bo4 = *(const float4*)(bo + ct * 32 + c4 * 4);
            float4 st;
            st.x = v0.x + v1.x + bo4.x; st.y = v0.y + v1.y + bo4.y;
            st.z = v0.z + v1.z + bo4.z; st.w = v0.w + v1.w + bo4.w;
            *(float4*)(out + ((long)i * NJ + row) * NC + ct * 32 + c4 * 4) = st;
        }
    }
}

// ---------------------------------------------------------------------------
extern "C" void kernel_launch(void* const* d_in, const int* in_sizes, int n_in,
                              void* d_out, int out_size, void* d_ws, size_t ws_size,
                              hipStream_t stream) {
    const float* x     = (const float*)d_in[0];
    const float* mask  = (const float*)d_in[1];
    const float* ln_w  = (const float*)d_in[3];
    const float* ln_b  = (const float*)d_in[4];
    const float* w_tri = (const float*)d_in[5];
    const float* wq    = (const float*)d_in[6];
    const float* wk    = (const float*)d_in[7];
    const float* wv    = (const float*)d_in[8];
    const float* wg    = (const float*)d_in[9];
    const float* bg    = (const float*)d_in[10];
    const float* wo    = (const float*)d_in[11];
    const float* bo    = (const float*)d_in[12];
    float* out = (float*)d_out;

    char* p = (char*)d_ws;
    float* tswz = (float*)p; p += (long)NH * NI * NJ * sizeof(float);
    unsigned short* Wt_all   = (unsigned short*)p; p += 4 * 128 * 128 * sizeof(unsigned short);
    unsigned short* Wto      = (unsigned short*)p; p += 128 * 128 * sizeof(unsigned short);
    unsigned short* Wtri_pad = (unsigned short*)p; p += 32 * 128 * sizeof(unsigned short);

    hipLaunchKernelGGL(convert_weights, dim3(336), dim3(256), 0, stream,
                       wq, wk, wv, wg, wo, w_tri, Wt_all, Wto, Wtri_pad);
    hipLaunchKernelGGL(ln_tri, dim3(TOKS / 64), dim3(256), 0, stream,
                       x, ln_w, ln_b, Wtri_pad, tswz);
    hipLaunchKernelGGL(attn_mega, dim3(NI), dim3(1024), 0, stream,
                       x, ln_w, ln_b, Wt_all, tswz, mask, Wto, bg, bo, out);
}

// Round 13
// 173.424 us; speedup vs baseline: 1.2577x; 1.2577x over previous
//
#include <hip/hip_runtime.h>
#include <math.h>

// B=1, I=J=256, C=128, H=4, CH=32
#define NI 256
#define NJ 256
#define NC 128
#define NH 4
#define NCH 32
#define TOKS ((long)NI * NJ)

typedef __attribute__((ext_vector_type(8)))  __bf16        bf16x8;
typedef __attribute__((ext_vector_type(8)))  unsigned short u16x8;
typedef __attribute__((ext_vector_type(4)))  unsigned int   u32x4;
typedef __attribute__((ext_vector_type(16))) float         f32x16;

__device__ __forceinline__ unsigned short f2bf(float f) {
    unsigned u = __builtin_bit_cast(unsigned, f);
    u += 0x7fffu + ((u >> 16) & 1u);          // RNE
    return (unsigned short)(u >> 16);
}
__device__ __forceinline__ float bf2f(unsigned short s) {
    return __builtin_bit_cast(float, ((unsigned)s) << 16);
}
__device__ __forceinline__ float exp2_fast(float x) {
    float r;
    asm("v_exp_f32 %0, %1" : "=v"(r) : "v"(x));   // D = 2^S0
    return r;
}
__device__ __forceinline__ f32x16 fzero16() {
    f32x16 z;
#pragma unroll
    for (int r = 0; r < 16; ++r) z[r] = 0.f;
    return z;
}
__device__ __forceinline__ f32x16 mfma16(bf16x8 a, bf16x8 b, f32x16 c) {
    return __builtin_amdgcn_mfma_f32_32x32x16_bf16(a, b, c, 0, 0, 0);
}

#define LOG2E 1.4426950408889634f

// ---------------------------------------------------------------------------
// Kernel 0: transpose+convert weights to bf16. w_tri is pre-scaled by log2e
// (softmax uses raw v_exp_f32 = 2^x; all logit terms carry the log2e factor).
// ---------------------------------------------------------------------------
__global__ __launch_bounds__(256) void convert_weights(
    const float* __restrict__ wq, const float* __restrict__ wk,
    const float* __restrict__ wv, const float* __restrict__ wg,
    const float* __restrict__ wo, const float* __restrict__ w_tri,
    unsigned short* __restrict__ Wt_all, unsigned short* __restrict__ Wto,
    unsigned short* __restrict__ Wtri_pad)
{
    int id = blockIdx.x * 256 + threadIdx.x;          // 0..86015
    if (id < 4 * 16384) {
        int m = id >> 14, r = id & 16383;
        int kk = r >> 7, c = r & 127;
        const float* W = (m == 0) ? wq : (m == 1) ? wk : (m == 2) ? wv : wg;
        Wt_all[(m * 128 + c) * 128 + kk] = f2bf(W[kk * 128 + c]);
    } else if (id < 5 * 16384) {
        int r = id - 4 * 16384;
        int kk = r >> 7, c = r & 127;
        Wto[c * 128 + kk] = f2bf(wo[kk * 128 + c]);
    } else {
        int r = id - 5 * 16384;                        // 0..4095
        int col = r >> 7, kk = r & 127;
        Wtri_pad[col * 128 + kk] = (col < NH) ? f2bf(w_tri[kk * NH + col] * LOG2E)
                                              : (unsigned short)0;
    }
}

// ---------------------------------------------------------------------------
// Kernel 1: LayerNorm + MFMA projections (q,k,v,g) + tri bias via MFMA.
// q is scaled by CH^-0.5 * log2e (exp2 softmax). tri bias scattered directly
// into the swizzled tswz layout (accT C-fragment == S^T C-fragment layout).
// Epilogue: q/k/v/g C-fragments transposed through the xn LDS buffer so
// global stores are short8 vectors.
// ---------------------------------------------------------------------------
#define XNP 136
__global__ __launch_bounds__(256, 2) void ln_proj_mfma(
    const float* __restrict__ x, const float* __restrict__ ln_w, const float* __restrict__ ln_b,
    const unsigned short* __restrict__ Wt_all, const unsigned short* __restrict__ Wtri_pad,
    const float* __restrict__ bg,
    unsigned short* __restrict__ q, unsigned short* __restrict__ k,
    unsigned short* __restrict__ v, unsigned short* __restrict__ g,
    float* __restrict__ tswz)
{
    __shared__ unsigned short xn[64 * XNP];   // ~17.4 KB (reused as store-staging)
    const int tid = threadIdx.x;
    const long tok0 = (long)blockIdx.x * 64;

    const int lane8 = tid & 7;
#pragma unroll
    for (int p = 0; p < 2; ++p) {
        const int t = p * 32 + (tid >> 3);
        const float4* xrow = (const float4*)(x + (tok0 + t) * NC + lane8 * 16);
        float4 xv[4];
        float s = 0.f;
#pragma unroll
        for (int u = 0; u < 4; ++u) {
            xv[u] = xrow[u];
            s += xv[u].x + xv[u].y + xv[u].z + xv[u].w;
        }
#pragma unroll
        for (int off = 4; off; off >>= 1) s += __shfl_down(s, off, 8);
        const float mu = __shfl(s, 0, 8) * (1.f / (float)NC);
        float s2 = 0.f;
#pragma unroll
        for (int u = 0; u < 4; ++u) {
            float dx;
            dx = xv[u].x - mu; s2 += dx * dx;
            dx = xv[u].y - mu; s2 += dx * dx;
            dx = xv[u].z - mu; s2 += dx * dx;
            dx = xv[u].w - mu; s2 += dx * dx;
        }
#pragma unroll
        for (int off = 4; off; off >>= 1) s2 += __shfl_down(s2, off, 8);
        const float rstd = rsqrtf(__shfl(s2, 0, 8) * (1.f / (float)NC) + 1e-5f);
#pragma unroll
        for (int u = 0; u < 4; ++u) {
            const int c = lane8 * 16 + u * 4;
            const float4 lw = *(const float4*)(ln_w + c);
            const float4 lb = *(const float4*)(ln_b + c);
            float o0 = (xv[u].x - mu) * rstd * lw.x + lb.x;
            float o1 = (xv[u].y - mu) * rstd * lw.y + lb.y;
            float o2 = (xv[u].z - mu) * rstd * lw.z + lb.z;
            float o3 = (xv[u].w - mu) * rstd * lw.w + lb.w;
            unsigned p0 = (unsigned)f2bf(o0) | ((unsigned)f2bf(o1) << 16);
            unsigned p1 = (unsigned)f2bf(o2) | ((unsigned)f2bf(o3) << 16);
            *(unsigned*)&xn[t * XNP + c]     = p0;
            *(unsigned*)&xn[t * XNP + c + 2] = p1;
        }
    }
    __syncthreads();

    const int w = tid >> 6, L = tid & 63, lh = L >> 5, lc = L & 31;
    f32x16 acc[2][4], accT[2];
#pragma unroll
    for (int mt = 0; mt < 2; ++mt) {
        accT[mt] = fzero16();
#pragma unroll
        for (int nt = 0; nt < 4; ++nt) acc[mt][nt] = fzero16();
    }

#pragma unroll
    for (int k0 = 0; k0 < 8; ++k0) {
        bf16x8 a0 = *(const bf16x8*)&xn[(lc)      * XNP + k0 * 16 + lh * 8];
        bf16x8 a1 = *(const bf16x8*)&xn[(32 + lc) * XNP + k0 * 16 + lh * 8];
#pragma unroll
        for (int nt = 0; nt < 4; ++nt) {
            const int ntile = w + 4 * nt;
            bf16x8 b = *(const bf16x8*)&Wt_all[(ntile * 32 + lc) * 128 + k0 * 16 + lh * 8];
            acc[0][nt] = mfma16(a0, b, acc[0][nt]);
            acc[1][nt] = mfma16(a1, b, acc[1][nt]);
        }
        bf16x8 bt = *(const bf16x8*)&Wtri_pad[lc * 128 + k0 * 16 + lh * 8];
        accT[0] = mfma16(a0, bt, accT[0]);
        accT[1] = mfma16(a1, bt, accT[1]);
    }

    const int a_row = (int)(tok0 >> 8);
    const int b0    = (int)(tok0 & 255);
    int rowl[16];
#pragma unroll
    for (int r = 0; r < 16; ++r) rowl[r] = (r & 3) + 8 * (r >> 2) + 4 * lh;

    // tri bias -> tswz (pre-swizzled, fused)
    if (lc < NH) {
        const int qt_i = a_row >> 5;
        const int lsw  = ((a_row & 31) + 32 * lh) * 16;
#pragma unroll
        for (int mt = 0; mt < 2; ++mt) {
            float* dst = tswz + ((long)((lc * 8 + qt_i) * 8 + (b0 >> 5) + mt)) * 1024 + lsw;
#pragma unroll
            for (int u = 0; u < 4; ++u)
                *(float4*)(dst + u * 4) = make_float4(accT[mt][4*u],   accT[mt][4*u+1],
                                                      accT[mt][4*u+2], accT[mt][4*u+3]);
        }
    }

    // q/k/v/g: transpose through LDS (reuse xn), then vectorized stores.
    const float bgv = bg[w * 32 + lc];
#pragma unroll
    for (int nt = 0; nt < 4; ++nt) {
        unsigned short* O = (nt == 0) ? q : (nt == 1) ? k : (nt == 2) ? v : g;
        __syncthreads();                      // previous xn readers done
#pragma unroll
        for (int mt = 0; mt < 2; ++mt) {
#pragma unroll
            for (int r = 0; r < 16; ++r) {
                const int row = mt * 32 + rowl[r];
                float val = acc[mt][nt][r];
                if (nt == 0) val *= 0.25503486f;                 // CH^-0.5 * log2e
                if (nt == 3) val = __builtin_amdgcn_rcpf(1.f + __expf(-(val + bgv)));
                xn[row * XNP + w * 32 + lc] = f2bf(val);
            }
        }
        __syncthreads();
#pragma unroll
        for (int it = 0; it < 4; ++it) {
            const int row = tid >> 2, cc = (tid & 3) * 8;
            *(u16x8*)(O + (((long)a_row * NH + it) * NJ + b0 + row) * NCH + cc) =
                *(const u16x8*)&xn[row * XNP + it * 32 + cc];
        }
    }
}

// ---------------------------------------------------------------------------
// Kernel 2: fused attention + gating + output projection, head-pipelined.
// Block = (i, qh): 128 queries, 256 threads (wave w -> q-tile qh*4+w).
// K/V double-buffered in LDS; global loads for head h+1 issued before head
// h's t-loop (T14: HBM latency hides under compute). g read from global.
// Softmax uses raw v_exp_f32 (logits pre-scaled by log2e).
// ---------------------------------------------------------------------------
#define KSP 40    // Ks row stride (shorts)
#define VTP 264   // Vt row stride (shorts)
#define OSP 36    // outs row stride (floats)
__global__ __launch_bounds__(256, 2) void attn_fused(
    const unsigned short* __restrict__ q, const unsigned short* __restrict__ k,
    const unsigned short* __restrict__ v, const unsigned short* __restrict__ g,
    const float* __restrict__ tswz, const float* __restrict__ mask,
    const unsigned short* __restrict__ Wto, const float* __restrict__ bo,
    float* __restrict__ out)
{
    __shared__ char smem[75776];
    // [0..40960)   : Ks double buffer (2 x 256*40*2 = 2 x 20480)
    // [40960..74752): Vt double buffer (2 x 32*264*2 = 2 x 16896)
    // [74752..75776): maskb (256 floats)
    float* maskb = (float*)(smem + 74752);
    float* outs  = (float*)smem;             // epilogue reuse: 128*36*4 = 18432

    const int i = blockIdx.x, qh = blockIdx.y;
    const int tid = threadIdx.x;
    const int w = tid >> 6, L = tid & 63, lh = L >> 5, lc = L & 31;
    const int qt = qh * 4 + w;               // q-tile 0..7
    const int qrow = qt * 32 + lc;           // this lane's query

    maskb[tid] = (1.0e9f * LOG2E) * (mask[i * NJ + tid] - 1.0f);

    // ---- prefetch head 0 staging into registers ----
    bf16x8 kreg[4];
    u16x8  vreg[4];
    {
        const long base0 = (long)i * NH * NJ * NCH;
#pragma unroll
        for (int it = 0; it < 4; ++it) {
            const int idx = it * 256 + tid;
            const int key = idx >> 2, c8 = (idx & 3) * 8;
            kreg[it] = *(const bf16x8*)(k + base0 + key * NCH + c8);
        }
#pragma unroll
        for (int u = 0; u < 4; ++u)
            vreg[u] = *(const u16x8*)(v + base0 + (long)tid * NCH + u * 8);
    }

    f32x16 outacc[4];
#pragma unroll
    for (int ct = 0; ct < 4; ++ct) outacc[ct] = fzero16();

#pragma unroll
    for (int h = 0; h < NH; ++h) {
        unsigned short* Ks = (unsigned short*)(smem + (h & 1) * 20480);
        unsigned short* Vt = (unsigned short*)(smem + 40960 + (h & 1) * 16896);
        const long base = ((long)i * NH + h) * NJ * NCH;

        if (h) __syncthreads();              // buf[h&1] readers (head h-2) done
        // ---- ds_write staged registers into buf[h&1] ----
#pragma unroll
        for (int it = 0; it < 4; ++it) {
            const int idx = it * 256 + tid;
            const int key = idx >> 2, c8 = (idx & 3) * 8;
            *(bf16x8*)&Ks[key * KSP + c8] = kreg[it];
        }
#pragma unroll
        for (int u = 0; u < 8; ++u) {
            Vt[(u)      * VTP + tid] = vreg[0][u];
            Vt[(u + 8)  * VTP + tid] = vreg[1][u];
            Vt[(u + 16) * VTP + tid] = vreg[2][u];
            Vt[(u + 24) * VTP + tid] = vreg[3][u];
        }
        __syncthreads();

        // ---- issue next head's staging loads (latency hides under t-loop) ----
        if (h < NH - 1) {
            const long basen = base + (long)NJ * NCH;
#pragma unroll
            for (int it = 0; it < 4; ++it) {
                const int idx = it * 256 + tid;
                const int key = idx >> 2, c8 = (idx & 3) * 8;
                kreg[it] = *(const bf16x8*)(k + basen + key * NCH + c8);
            }
#pragma unroll
            for (int u = 0; u < 4; ++u)
                vreg[u] = *(const u16x8*)(v + basen + (long)tid * NCH + u * 8);
        }

        // ---- Q B-frag + g prefetch (consumed at end of head) ----
        const bf16x8 a0 = *(const bf16x8*)(q + base + (long)qrow * NCH + lh * 8);
        const bf16x8 a1 = *(const bf16x8*)(q + base + (long)qrow * NCH + 16 + lh * 8);
        ushort4 gv[4];
#pragma unroll
        for (int gg = 0; gg < 4; ++gg)
            gv[gg] = *(const ushort4*)(g + base + (long)qrow * NCH + gg * 8 + 4 * lh);
        const float* tbase = tswz + ((long)(h * 8 + qt) * 8) * 1024 + (long)L * 16;

        float ls = 0.f;
        f32x16 O = fzero16();

#pragma unroll
        for (int t = 0; t < 8; ++t) {
            // S^T tile: q = lc, keys = t*32 + (reg&3)+8*(reg>>2)+4*lh
            bf16x8 kb0 = *(const bf16x8*)&Ks[(t * 32 + lc) * KSP + lh * 8];
            bf16x8 kb1 = *(const bf16x8*)&Ks[(t * 32 + lc) * KSP + 16 + lh * 8];
            f32x16 s = fzero16();
            s = mfma16(kb0, a0, s);
            s = mfma16(kb1, a1, s);

            // bias (pre-swizzled) + exp2 + per-lane sum; pack bf16 (RNE)
            unsigned pk[8];
            const float* tv = tbase + (long)t * 1024;
#pragma unroll
            for (int gg = 0; gg < 4; ++gg) {
                const float4 tb = *(const float4*)(tv + gg * 4);
                const float4 mb = *(const float4*)&maskb[t * 32 + gg * 8 + 4 * lh];
                const float p0 = exp2_fast(fminf(s[4 * gg + 0] + tb.x + mb.x, 43.4f));
                const float p1 = exp2_fast(fminf(s[4 * gg + 1] + tb.y + mb.y, 43.4f));
                const float p2 = exp2_fast(fminf(s[4 * gg + 2] + tb.z + mb.z, 43.4f));
                const float p3 = exp2_fast(fminf(s[4 * gg + 3] + tb.w + mb.w, 43.4f));
                ls += (p0 + p1) + (p2 + p3);
                pk[2 * gg]     = (unsigned)f2bf(p0) | ((unsigned)f2bf(p1) << 16);
                pk[2 * gg + 1] = (unsigned)f2bf(p2) | ((unsigned)f2bf(p3) << 16);
            }

            // O^T += V^T @ P^T (in-register B-frag via lane^32 exchange)
#pragma unroll
            for (int ss = 0; ss < 2; ++ss) {
                const unsigned give0 = lh ? pk[4 * ss]     : pk[4 * ss + 2];
                const unsigned give1 = lh ? pk[4 * ss + 1] : pk[4 * ss + 3];
                const unsigned t0 = __shfl_xor(give0, 32);
                const unsigned t1 = __shfl_xor(give1, 32);
                u32x4 bw;
                bw[0] = lh ? t0 : pk[4 * ss];
                bw[1] = lh ? t1 : pk[4 * ss + 1];
                bw[2] = lh ? pk[4 * ss + 2] : t0;
                bw[3] = lh ? pk[4 * ss + 3] : t1;
                const bf16x8 pb = __builtin_bit_cast(bf16x8, bw);
                const bf16x8 va = *(const bf16x8*)&Vt[lc * VTP + t * 32 + ss * 16 + lh * 8];
                O = mfma16(va, pb, O);
            }
        }

        // ---- normalize + gate (g from prefetched regs); pack OG^T to bf16 ----
        ls += __shfl_xor(ls, 32);
        const float rl = __builtin_amdgcn_rcpf(ls);
        unsigned pk2[8];
#pragma unroll
        for (int gg = 0; gg < 4; ++gg) {
            const float o0 = O[4 * gg + 0] * rl * bf2f(gv[gg].x);
            const float o1 = O[4 * gg + 1] * rl * bf2f(gv[gg].y);
            const float o2 = O[4 * gg + 2] * rl * bf2f(gv[gg].z);
            const float o3 = O[4 * gg + 3] * rl * bf2f(gv[gg].w);
            pk2[2 * gg]     = (unsigned)f2bf(o0) | ((unsigned)f2bf(o1) << 16);
            pk2[2 * gg + 1] = (unsigned)f2bf(o2) | ((unsigned)f2bf(o3) << 16);
        }

        // ---- out^T += Wo_h^T @ OG_h^T ----
#pragma unroll
        for (int ss = 0; ss < 2; ++ss) {
            const unsigned give0 = lh ? pk2[4 * ss]     : pk2[4 * ss + 2];
            const unsigned give1 = lh ? pk2[4 * ss + 1] : pk2[4 * ss + 3];
            const unsigned t0 = __shfl_xor(give0, 32);
            const unsigned t1 = __shfl_xor(give1, 32);
            u32x4 bw;
            bw[0] = lh ? t0 : pk2[4 * ss];
            bw[1] = lh ? t1 : pk2[4 * ss + 1];
            bw[2] = lh ? pk2[4 * ss + 2] : t0;
            bw[3] = lh ? pk2[4 * ss + 3] : t1;
            const bf16x8 ogb = __builtin_bit_cast(bf16x8, bw);
#pragma unroll
            for (int ct = 0; ct < 4; ++ct) {
                const bf16x8 wa = *(const bf16x8*)&Wto[(ct * 32 + lc) * 128 + h * 32 + ss * 16 + lh * 8];
                outacc[ct] = mfma16(wa, ogb, outacc[ct]);
            }
        }
    }

    // ---- epilogue: per cout-tile, stage through LDS, coalesced stores ----
    int rowl[16];
#pragma unroll
    for (int r = 0; r < 16; ++r) rowl[r] = (r & 3) + 8 * (r >> 2) + 4 * lh;
#pragma unroll
    for (int ct = 0; ct < 4; ++ct) {
        __syncthreads();                      // protect smem reuse / prev tile reads
#pragma unroll
        for (int r = 0; r < 16; ++r)
            outs[(w * 32 + lc) * OSP + rowl[r]] = outacc[ct][r];
        __syncthreads();
#pragma unroll
        for (int it = 0; it < 4; ++it) {
            const int fi = it * 256 + tid;    // 0..1023 float4s
            const int row = fi >> 3, c4 = fi & 7;
            const float4 vv = *(const float4*)&outs[row * OSP + c4 * 4];
            const float4 bo4 = *(const float4*)(bo + ct * 32 + c4 * 4);
            float4 st;
            st.x = vv.x + bo4.x; st.y = vv.y + bo4.y;
            st.z = vv.z + bo4.z; st.w = vv.w + bo4.w;
            *(float4*)(out + ((long)i * NJ + qh * 128 + row) * NC + ct * 32 + c4 * 4) = st;
        }
    }
}

// ---------------------------------------------------------------------------
extern "C" void kernel_launch(void* const* d_in, const int* in_sizes, int n_in,
                              void* d_out, int out_size, void* d_ws, size_t ws_size,
                              hipStream_t stream) {
    const float* x     = (const float*)d_in[0];
    const float* mask  = (const float*)d_in[1];
    const float* ln_w  = (const float*)d_in[3];
    const float* ln_b  = (const float*)d_in[4];
    const float* w_tri = (const float*)d_in[5];
    const float* wq    = (const float*)d_in[6];
    const float* wk    = (const float*)d_in[7];
    const float* wv    = (const float*)d_in[8];
    const float* wg    = (const float*)d_in[9];
    const float* bg    = (const float*)d_in[10];
    const float* wo    = (const float*)d_in[11];
    const float* bo    = (const float*)d_in[12];
    float* out = (float*)d_out;

    char* p = (char*)d_ws;
    const long QB  = TOKS * NC * sizeof(unsigned short); // 16.78 MB
    unsigned short* q  = (unsigned short*)p; p += QB;
    unsigned short* k  = (unsigned short*)p; p += QB;
    unsigned short* v  = (unsigned short*)p; p += QB;
    unsigned short* g  = (unsigned short*)p; p += QB;
    float* tswz = (float*)p; p += (long)NH * NI * NJ * sizeof(float);
    unsigned short* Wt_all   = (unsigned short*)p; p += 4 * 128 * 128 * sizeof(unsigned short);
    unsigned short* Wto      = (unsigned short*)p; p += 128 * 128 * sizeof(unsigned short);
    unsigned short* Wtri_pad = (unsigned short*)p; p += 32 * 128 * sizeof(unsigned short);

    hipLaunchKernelGGL(convert_weights, dim3(336), dim3(256), 0, stream,
                       wq, wk, wv, wg, wo, w_tri, Wt_all, Wto, Wtri_pad);
    hipLaunchKernelGGL(ln_proj_mfma, dim3(TOKS / 64), dim3(256), 0, stream,
                       x, ln_w, ln_b, Wt_all, Wtri_pad, bg, q, k, v, g, tswz);
    hipLaunchKernelGGL(attn_fused, dim3(NI, 2), dim3(256), 0, stream,
                       q, k, v, g, tswz, mask, Wto, bo, out);
}